// Round 2
// baseline (205.910 us; speedup 1.0000x reference)
//
#include <hip/hip_runtime.h>
#include <hip/hip_bf16.h>
#include <cstdint>

// ---------------------------------------------------------------------------
// MLPDecoder: logit[e] = relu([zu, zv, |zu-zv|] @ W1 + b1) @ W2 + b2
// Round-2 restructuring:
//   feat@W1 = zu@W1a + zv@W1b + |zu-zv|@W1c   (W1 split by k-thirds)
//   Kernel A: P[node] = [z@W1a | z@W1b]  (bf16, 100K x 256) + cast z->bf16
//             + pack W1c into MFMA B-frag order (tail blocks)
//   Kernel B: per-edge K=128 MFMA for the |zu-zv| term, + gathered P[u]+P[v]
//             in the epilogue. Each wave owns all M (mt=4) so W1c is read
//             exactly once per block (32 KB, kills the 1.5 GB B-traffic of r1).
// ---------------------------------------------------------------------------

typedef __bf16 bf16_t;
typedef __bf16 bf16x8 __attribute__((ext_vector_type(8)));
typedef float  floatx4 __attribute__((ext_vector_type(4)));

#define DIM 128
#define LDA 136              // 128 + 8 pad (16B) -> 272B row, 2-way alias only (free)
#define NB_TILE 64           // nodes per block (kernel A)
#define E_TILE 64            // edges per block (kernel B)
#define PACK_BLOCKS 8        // tail blocks of kernel A that pack W1c

__device__ inline float bflo(unsigned w) { return __uint_as_float(w << 16); }
__device__ inline float bfhi(unsigned w) { return __uint_as_float(w & 0xffff0000u); }
__device__ inline float bf2f(unsigned short u) { return __uint_as_float(((unsigned)u) << 16); }

// ===========================================================================
// Kernel A: cast z -> zb (bf16), P = [z@W1a | z@W1b] (bf16), pack W1c.
// Grid = ceil(Nn/64) + PACK_BLOCKS.
// ===========================================================================
__global__ __launch_bounds__(256)
void precompute_kernel(const float* __restrict__ z,
                       const float* __restrict__ W1,
                       bf16_t* __restrict__ zb,
                       bf16_t* __restrict__ P,
                       bf16_t* __restrict__ Wc,
                       int Nn, int nblk) {
    __shared__ __align__(16) bf16_t A[NB_TILE * LDA];
    const int tid = threadIdx.x;

    if ((int)blockIdx.x >= nblk) {
        // ---- pack W1c [rows 256..384 of W1] into B-frag order ----
        // frag f = ks*8+nt; lane l holds B[k=ks*32+(l>>4)*8+j][n=nt*16+(l&15)]
        int pid = ((int)blockIdx.x - nblk) * 256 + tid;   // 0..2047
        int lane = pid & 63;
        int fidx = pid >> 6;                              // 0..31
        int nt = fidx & 7, ks = fidx >> 3;
        int n  = nt * 16 + (lane & 15);
        int k0 = ks * 32 + (lane >> 4) * 8;
        bf16x8 o;
#pragma unroll
        for (int j = 0; j < 8; ++j) o[j] = (bf16_t)W1[(256 + k0 + j) * DIM + n];
        reinterpret_cast<bf16x8*>(Wc)[fidx * 64 + lane] = o;
        return;
    }

    const int node0 = (int)blockIdx.x * NB_TILE;
    // ---- stage z tile -> bf16 LDS + write zb (coalesced) ----
#pragma unroll
    for (int i = 0; i < 4; ++i) {
        int t = i * 256 + tid;
        int m = t >> 4, c = (t & 15) * 8;
        int node = node0 + m;
        int nc = node < Nn ? node : Nn - 1;
        const float4* src = reinterpret_cast<const float4*>(z + (size_t)nc * DIM + c);
        float4 a = src[0], b = src[1];
        bf16x8 o;
        o[0]=(bf16_t)a.x; o[1]=(bf16_t)a.y; o[2]=(bf16_t)a.z; o[3]=(bf16_t)a.w;
        o[4]=(bf16_t)b.x; o[5]=(bf16_t)b.y; o[6]=(bf16_t)b.z; o[7]=(bf16_t)b.w;
        *reinterpret_cast<bf16x8*>(&A[m * LDA + c]) = o;
        if (node < Nn)
            *reinterpret_cast<bf16x8*>(zb + (size_t)node * DIM + c) = o;
    }
    __syncthreads();

    const int wave = tid >> 6, lane = tid & 63;
    const int l15 = lane & 15, quad = lane >> 4;

    floatx4 acc[4][4];
#pragma unroll
    for (int mt = 0; mt < 4; ++mt)
#pragma unroll
        for (int nt = 0; nt < 4; ++nt) acc[mt][nt] = (floatx4)0.0f;

    // wave owns n' = wave*64 .. +63 of the 256-wide [W1a|W1b] B matrix
#pragma unroll
    for (int ks = 0; ks < 4; ++ks) {
        bf16x8 bfrag[4];
#pragma unroll
        for (int nt = 0; nt < 4; ++nt) {
            int np = wave * 64 + nt * 16 + l15;
            int k0 = ks * 32 + quad * 8;
            // wave-uniform branch: waves 0,1 -> W1a, waves 2,3 -> W1b
            const float* wsrc = (np < DIM) ? &W1[(size_t)k0 * DIM + np]
                                           : &W1[(size_t)(DIM + k0) * DIM + (np - DIM)];
#pragma unroll
            for (int j = 0; j < 8; ++j) bfrag[nt][j] = (bf16_t)wsrc[(size_t)j * DIM];
        }
#pragma unroll
        for (int mt = 0; mt < 4; ++mt) {
            bf16x8 afrag = *reinterpret_cast<const bf16x8*>(
                &A[(mt * 16 + l15) * LDA + ks * 32 + quad * 8]);
#pragma unroll
            for (int nt = 0; nt < 4; ++nt)
                acc[mt][nt] = __builtin_amdgcn_mfma_f32_16x16x32_bf16(
                    afrag, bfrag[nt], acc[mt][nt], 0, 0, 0);
        }
    }

    // ---- store P (C layout: n=l15, m=quad*4+r). Per row a wave covers a
    // contiguous 128B slab -> L2 write-combines. ----
#pragma unroll
    for (int mt = 0; mt < 4; ++mt)
#pragma unroll
        for (int r = 0; r < 4; ++r) {
            int node = node0 + mt * 16 + quad * 4 + r;
            if (node < Nn) {
#pragma unroll
                for (int nt = 0; nt < 4; ++nt) {
                    int np = wave * 64 + nt * 16 + l15;
                    P[(size_t)node * 256 + np] = (bf16_t)acc[mt][nt][r];
                }
            }
        }
}

// ===========================================================================
// Kernel B: per-edge. A-tile = |zu-zv| (K=128), H-tile = P[u]+P[v].
// 4 waves: wave w owns nt {2w, 2w+1} (n = w*32..w*32+31), mt = 0..3 (all M).
// W1c read exactly once per block.
// ===========================================================================
__global__ __launch_bounds__(256)
void edge_kernel(const bf16_t* __restrict__ zb,
                 const bf16_t* __restrict__ P,
                 const bf16_t* __restrict__ Wc,
                 const int* __restrict__ ei,
                 const float* __restrict__ b1,
                 const float* __restrict__ W2,
                 const float* __restrict__ b2,
                 float* __restrict__ out, int E) {
    __shared__ __align__(16) bf16_t A[E_TILE * LDA];   // 17408 B
    __shared__ __align__(16) bf16_t H[E_TILE * LDA];   // 17408 B
    __shared__ float red[4][E_TILE];                   // 1024 B

    const int tid = threadIdx.x;
    const int ebase = (int)blockIdx.x * E_TILE;

    // ---- stage: gather zu,zv,Pa,Pb; build A=|zu-zv| and H=Pa+Pb ----
#pragma unroll
    for (int i = 0; i < 4; ++i) {
        int t = i * 256 + tid;
        int m = t >> 4, c = (t & 15) * 8;
        int e = ebase + m; if (e >= E) e = E - 1;
        int u = ei[e], v = ei[E + e];
        uint4 zu = *reinterpret_cast<const uint4*>(zb + (size_t)u * DIM + c);
        uint4 zv = *reinterpret_cast<const uint4*>(zb + (size_t)v * DIM + c);
        uint4 pa = *reinterpret_cast<const uint4*>(P + (size_t)u * 256 + c);
        uint4 pb = *reinterpret_cast<const uint4*>(P + (size_t)v * 256 + DIM + c);
        bf16x8 d, h;
        d[0]=(bf16_t)fabsf(bflo(zu.x)-bflo(zv.x));
        d[1]=(bf16_t)fabsf(bfhi(zu.x)-bfhi(zv.x));
        d[2]=(bf16_t)fabsf(bflo(zu.y)-bflo(zv.y));
        d[3]=(bf16_t)fabsf(bfhi(zu.y)-bfhi(zv.y));
        d[4]=(bf16_t)fabsf(bflo(zu.z)-bflo(zv.z));
        d[5]=(bf16_t)fabsf(bfhi(zu.z)-bfhi(zv.z));
        d[6]=(bf16_t)fabsf(bflo(zu.w)-bflo(zv.w));
        d[7]=(bf16_t)fabsf(bfhi(zu.w)-bfhi(zv.w));
        h[0]=(bf16_t)(bflo(pa.x)+bflo(pb.x));
        h[1]=(bf16_t)(bfhi(pa.x)+bfhi(pb.x));
        h[2]=(bf16_t)(bflo(pa.y)+bflo(pb.y));
        h[3]=(bf16_t)(bfhi(pa.y)+bfhi(pb.y));
        h[4]=(bf16_t)(bflo(pa.z)+bflo(pb.z));
        h[5]=(bf16_t)(bfhi(pa.z)+bfhi(pb.z));
        h[6]=(bf16_t)(bflo(pa.w)+bflo(pb.w));
        h[7]=(bf16_t)(bfhi(pa.w)+bfhi(pb.w));
        *reinterpret_cast<bf16x8*>(&A[m * LDA + c]) = d;
        *reinterpret_cast<bf16x8*>(&H[m * LDA + c]) = h;
    }
    __syncthreads();

    const int wave = tid >> 6, lane = tid & 63;
    const int l15 = lane & 15, quad = lane >> 4;

    float b1v[2], w2v[2];
#pragma unroll
    for (int nt = 0; nt < 2; ++nt) {
        int n = (wave * 2 + nt) * 16 + l15;
        b1v[nt] = b1[n];
        w2v[nt] = W2[n];
    }

    floatx4 acc[4][2];
#pragma unroll
    for (int mt = 0; mt < 4; ++mt)
#pragma unroll
        for (int nt = 0; nt < 2; ++nt) acc[mt][nt] = (floatx4)0.0f;

    const bf16x8* WcF = reinterpret_cast<const bf16x8*>(Wc);
#pragma unroll
    for (int ks = 0; ks < 4; ++ks) {
        bf16x8 bfrag[2];
#pragma unroll
        for (int nt = 0; nt < 2; ++nt)
            bfrag[nt] = WcF[(ks * 8 + wave * 2 + nt) * 64 + lane];
#pragma unroll
        for (int mt = 0; mt < 4; ++mt) {
            bf16x8 afrag = *reinterpret_cast<const bf16x8*>(
                &A[(mt * 16 + l15) * LDA + ks * 32 + quad * 8]);
#pragma unroll
            for (int nt = 0; nt < 2; ++nt)
                acc[mt][nt] = __builtin_amdgcn_mfma_f32_16x16x32_bf16(
                    afrag, bfrag[nt], acc[mt][nt], 0, 0, 0);
        }
    }

    // ---- epilogue: h = mfma + H + b1; relu; dot W2; 16-lane butterfly ----
    const unsigned short* Hs = reinterpret_cast<const unsigned short*>(H);
#pragma unroll
    for (int mt = 0; mt < 4; ++mt)
#pragma unroll
        for (int r = 0; r < 4; ++r) {
            int m = mt * 16 + quad * 4 + r;
            float s = 0.f;
#pragma unroll
            for (int nt = 0; nt < 2; ++nt) {
                int n = (wave * 2 + nt) * 16 + l15;
                float h = acc[mt][nt][r] + b1v[nt] + bf2f(Hs[m * LDA + n]);
                h = fmaxf(h, 0.f);
                s += h * w2v[nt];
            }
            s += __shfl_xor(s, 1);
            s += __shfl_xor(s, 2);
            s += __shfl_xor(s, 4);
            s += __shfl_xor(s, 8);
            if (l15 == 0) red[wave][m] = s;
        }
    __syncthreads();

    if (tid < E_TILE) {
        int e = ebase + tid;
        if (e < E) out[e] = red[0][tid] + red[1][tid] + red[2][tid] + red[3][tid] + b2[0];
    }
}

// ===========================================================================
// Fallback path (round-1 proven kernels) if ws is too small for P.
// ===========================================================================
#define K3 384
#define ROW_ELEMS 392
#define N_KSTEP 12
#define N_NTILE 8

__global__ void pack_w1_kernel(const float* __restrict__ W1, bf16_t* __restrict__ Wp) {
    int f = blockIdx.x * 256 + threadIdx.x;
    if (f >= N_KSTEP * N_NTILE * 64) return;
    int lane = f & 63;
    int nt   = (f >> 6) & 7;
    int ks   = f >> 9;
    int n  = nt * 16 + (lane & 15);
    int k0 = ks * 32 + (lane >> 4) * 8;
    bf16x8 o;
#pragma unroll
    for (int j = 0; j < 8; ++j) o[j] = (bf16_t)W1[(k0 + j) * DIM + n];
    reinterpret_cast<bf16x8*>(Wp)[f] = o;
}

__global__ __launch_bounds__(256)
void decode_fallback(const float* __restrict__ zsrc,
                     const int* __restrict__ ei,
                     const bf16_t* __restrict__ Wp,
                     const float* __restrict__ b1,
                     const float* __restrict__ W2,
                     const float* __restrict__ b2,
                     float* __restrict__ out, int E) {
    __shared__ __align__(16) bf16_t Atile[E_TILE * ROW_ELEMS];
    __shared__ float red[2][E_TILE];
    const int tid = threadIdx.x;
    const int ebase = blockIdx.x * E_TILE;
#pragma unroll
    for (int i = 0; i < 8; ++i) {
        int half  = i * 16 + (tid >> 4);
        int m     = half >> 1;
        int which = half & 1;
        int e = ebase + m; if (e >= E) e = E - 1;
        int node = ei[which * E + e];
        int l16 = tid & 15;
        bf16_t* dst = &Atile[m * ROW_ELEMS + which * DIM + l16 * 8];
        const float4* src = reinterpret_cast<const float4*>(
            zsrc + (size_t)node * DIM + l16 * 8);
        float4 a = src[0], b = src[1];
        bf16x8 o;
        o[0]=(bf16_t)a.x; o[1]=(bf16_t)a.y; o[2]=(bf16_t)a.z; o[3]=(bf16_t)a.w;
        o[4]=(bf16_t)b.x; o[5]=(bf16_t)b.y; o[6]=(bf16_t)b.z; o[7]=(bf16_t)b.w;
        *reinterpret_cast<bf16x8*>(dst) = o;
    }
    __syncthreads();
#pragma unroll
    for (int i = 0; i < 4; ++i) {
        int chunk = i * 256 + tid;
        int m  = chunk >> 4;
        int cc = (chunk & 15) * 8;
        uint4 au = *reinterpret_cast<const uint4*>(&Atile[m * ROW_ELEMS + cc]);
        uint4 av = *reinterpret_cast<const uint4*>(&Atile[m * ROW_ELEMS + DIM + cc]);
        bf16x8 d;
        d[0]=(bf16_t)fabsf(bflo(au.x)-bflo(av.x));
        d[1]=(bf16_t)fabsf(bfhi(au.x)-bfhi(av.x));
        d[2]=(bf16_t)fabsf(bflo(au.y)-bflo(av.y));
        d[3]=(bf16_t)fabsf(bfhi(au.y)-bfhi(av.y));
        d[4]=(bf16_t)fabsf(bflo(au.z)-bflo(av.z));
        d[5]=(bf16_t)fabsf(bfhi(au.z)-bfhi(av.z));
        d[6]=(bf16_t)fabsf(bflo(au.w)-bflo(av.w));
        d[7]=(bf16_t)fabsf(bfhi(au.w)-bfhi(av.w));
        *reinterpret_cast<bf16x8*>(&Atile[m * ROW_ELEMS + 2 * DIM + cc]) = d;
    }
    __syncthreads();
    const int wave = tid >> 6, lane = tid & 63;
    const int wm = wave >> 1, wn = wave & 1;
    const int l15 = lane & 15, quad = lane >> 4;
    floatx4 acc[2][4];
#pragma unroll
    for (int mt = 0; mt < 2; ++mt)
#pragma unroll
        for (int nt = 0; nt < 4; ++nt) acc[mt][nt] = (floatx4)0.0f;
    float b1v[4], w2v[4];
#pragma unroll
    for (int nt = 0; nt < 4; ++nt) {
        int n = (wn * 4 + nt) * 16 + l15;
        b1v[nt] = b1[n];
        w2v[nt] = W2[n];
    }
    const bf16x8* WpF = reinterpret_cast<const bf16x8*>(Wp);
#pragma unroll
    for (int ks = 0; ks < N_KSTEP; ++ks) {
        bf16x8 bfrag[4];
#pragma unroll
        for (int nt = 0; nt < 4; ++nt)
            bfrag[nt] = WpF[(ks * N_NTILE + wn * 4 + nt) * 64 + lane];
#pragma unroll
        for (int mt = 0; mt < 2; ++mt) {
            int m = wm * 32 + mt * 16 + l15;
            bf16x8 afrag = *reinterpret_cast<const bf16x8*>(
                &Atile[m * ROW_ELEMS + ks * 32 + quad * 8]);
#pragma unroll
            for (int nt = 0; nt < 4; ++nt)
                acc[mt][nt] = __builtin_amdgcn_mfma_f32_16x16x32_bf16(
                    afrag, bfrag[nt], acc[mt][nt], 0, 0, 0);
        }
    }
    float partial[2][4];
#pragma unroll
    for (int mt = 0; mt < 2; ++mt)
#pragma unroll
        for (int r = 0; r < 4; ++r) {
            float s = 0.f;
#pragma unroll
            for (int nt = 0; nt < 4; ++nt) {
                float h = acc[mt][nt][r] + b1v[nt];
                h = fmaxf(h, 0.f);
                s += h * w2v[nt];
            }
            s += __shfl_xor(s, 1);
            s += __shfl_xor(s, 2);
            s += __shfl_xor(s, 4);
            s += __shfl_xor(s, 8);
            partial[mt][r] = s;
        }
    if (l15 == 0) {
#pragma unroll
        for (int mt = 0; mt < 2; ++mt)
#pragma unroll
            for (int r = 0; r < 4; ++r) {
                int m = wm * 32 + mt * 16 + quad * 4 + r;
                red[wn][m] = partial[mt][r];
            }
    }
    __syncthreads();
    if (tid < E_TILE) {
        int e = ebase + tid;
        if (e < E) out[e] = red[0][tid] + red[1][tid] + b2[0];
    }
}

// ===========================================================================
extern "C" void kernel_launch(void* const* d_in, const int* in_sizes, int n_in,
                              void* d_out, int out_size, void* d_ws, size_t ws_size,
                              hipStream_t stream) {
    const float* z  = (const float*)d_in[0];
    const int*   ei = (const int*)d_in[1];
    const float* W1 = (const float*)d_in[2];
    const float* b1 = (const float*)d_in[3];
    const float* W2 = (const float*)d_in[4];
    const float* b2 = (const float*)d_in[5];
    float* out = (float*)d_out;

    const int E  = in_sizes[1] / 2;
    const int Nn = in_sizes[0] / DIM;

    const size_t zb_bytes = (size_t)Nn * DIM * sizeof(bf16_t);     // 25.6 MB
    const size_t p_bytes  = (size_t)Nn * 256 * sizeof(bf16_t);     // 51.2 MB
    const size_t wc_bytes = 4 * 8 * 64 * 16;                       // 32 KB

    const int eblocks = (E + E_TILE - 1) / E_TILE;

    if (ws_size >= zb_bytes + p_bytes + wc_bytes) {
        bf16_t* zb = (bf16_t*)d_ws;
        bf16_t* P  = (bf16_t*)((char*)d_ws + zb_bytes);
        bf16_t* Wc = (bf16_t*)((char*)d_ws + zb_bytes + p_bytes);
        const int nblk = (Nn + NB_TILE - 1) / NB_TILE;
        hipLaunchKernelGGL(precompute_kernel, dim3(nblk + PACK_BLOCKS), dim3(256),
                           0, stream, z, W1, zb, P, Wc, Nn, nblk);
        hipLaunchKernelGGL(edge_kernel, dim3(eblocks), dim3(256), 0, stream,
                           zb, P, Wc, ei, b1, W2, b2, out, E);
    } else {
        // fallback: round-1 path (needs only 96 KB ws for packed W1)
        bf16_t* wp = (bf16_t*)d_ws;
        hipLaunchKernelGGL(pack_w1_kernel, dim3((N_KSTEP * N_NTILE * 64 + 255) / 256),
                           dim3(256), 0, stream, W1, wp);
        hipLaunchKernelGGL(decode_fallback, dim3(eblocks), dim3(256), 0, stream,
                           z, ei, wp, b1, W2, b2, out, E);
    }
}

// Round 3
// 197.508 us; speedup vs baseline: 1.0425x; 1.0425x over previous
//
#include <hip/hip_runtime.h>
#include <hip/hip_bf16.h>
#include <cstdint>

// ---------------------------------------------------------------------------
// MLPDecoder: logit[e] = relu([zu, zv, |zu-zv|] @ W1 + b1) @ W2 + b2
// Round-3:
//   feat@W1 = zu@W1a + zv@W1b + |zu-zv|@W1c
//   K0: pack ALL of W1 (384x128) into MFMA B-frag order (bf16)   [r1-proven]
//   K1: precompute P[node] = [z@W1a | z@W1b] bf16 + cast z->bf16.
//       B-frags now read lane-contiguous from packed Wp (fixes r2's
//       64-cacheline strided W1 loads that cost ~100us).
//   K2: edge kernel, K=128 MFMA for |zu-zv|@W1c + gathered P[u]+P[v].
//       Gathers batched (all 16 uint4 in flight) with VGPR headroom
//       (launch_bounds(256,4): LDS caps blocks/CU at 4 anyway).
// ---------------------------------------------------------------------------

typedef __bf16 bf16_t;
typedef __bf16 bf16x8 __attribute__((ext_vector_type(8)));
typedef float  floatx4 __attribute__((ext_vector_type(4)));

#define DIM 128
#define LDA 136              // 128 + 8 pad -> 272B rows; 2-way bank alias only (free)
#define NB_TILE 64
#define E_TILE 64
#define N_KSTEP 12           // full W1: 384/32
#define N_NTILE 8            // 128/16

__device__ inline float bflo(unsigned w) { return __uint_as_float(w << 16); }
__device__ inline float bfhi(unsigned w) { return __uint_as_float(w & 0xffff0000u); }
__device__ inline float bf2f(unsigned short u) { return __uint_as_float(((unsigned)u) << 16); }

// ===========================================================================
// K0: pack W1 [384,128] f32 -> bf16 MFMA B-frag order.
// frag f = ks*8+nt; lane l holds B[k=ks*32+(l>>4)*8+j][n=nt*16+(l&15)], j=0..7
// ===========================================================================
__global__ void pack_w1_kernel(const float* __restrict__ W1, bf16_t* __restrict__ Wp) {
    int f = blockIdx.x * 256 + threadIdx.x;     // 0 .. 12*8*64-1
    if (f >= N_KSTEP * N_NTILE * 64) return;
    int lane = f & 63;
    int nt   = (f >> 6) & 7;
    int ks   = f >> 9;
    int n  = nt * 16 + (lane & 15);
    int k0 = ks * 32 + (lane >> 4) * 8;
    bf16x8 o;
#pragma unroll
    for (int j = 0; j < 8; ++j) o[j] = (bf16_t)W1[(k0 + j) * DIM + n];
    reinterpret_cast<bf16x8*>(Wp)[f] = o;
}

// ===========================================================================
// K1: zb = bf16(z);  P = [z@W1a | z@W1b]  (bf16, Nn x 256)
// Wave w owns output cols n' = w*64 .. w*64+63 of the 256-wide B' = [W1a|W1b].
// B'[k][n'] for n'<128 is W1[k][n'] (frag ks=k/32, nt=n'/16);
//           for n'>=128 is W1[128+k][n'-128] (frag ks=4+k/32, nt=(n'-128)/16).
// ===========================================================================
__global__ __launch_bounds__(256)
void precompute_kernel(const float* __restrict__ z,
                       const bf16_t* __restrict__ Wp,
                       bf16_t* __restrict__ zb,
                       bf16_t* __restrict__ P,
                       int Nn) {
    __shared__ __align__(16) bf16_t A[NB_TILE * LDA];
    const int tid = threadIdx.x;
    const int node0 = (int)blockIdx.x * NB_TILE;

    // ---- stage z tile -> bf16 LDS + write zb (coalesced) ----
#pragma unroll
    for (int i = 0; i < 4; ++i) {
        int t = i * 256 + tid;
        int m = t >> 4, c = (t & 15) * 8;
        int node = node0 + m;
        int nc = node < Nn ? node : Nn - 1;
        const float4* src = reinterpret_cast<const float4*>(z + (size_t)nc * DIM + c);
        float4 a = src[0], b = src[1];
        bf16x8 o;
        o[0]=(bf16_t)a.x; o[1]=(bf16_t)a.y; o[2]=(bf16_t)a.z; o[3]=(bf16_t)a.w;
        o[4]=(bf16_t)b.x; o[5]=(bf16_t)b.y; o[6]=(bf16_t)b.z; o[7]=(bf16_t)b.w;
        *reinterpret_cast<bf16x8*>(&A[m * LDA + c]) = o;
        if (node < Nn)
            *reinterpret_cast<bf16x8*>(zb + (size_t)node * DIM + c) = o;
    }
    __syncthreads();

    const int wave = tid >> 6, lane = tid & 63;
    const int l15 = lane & 15, quad = lane >> 4;
    const bf16x8* WpF = reinterpret_cast<const bf16x8*>(Wp);

    floatx4 acc[4][4];
#pragma unroll
    for (int mt = 0; mt < 4; ++mt)
#pragma unroll
        for (int nt = 0; nt < 4; ++nt) acc[mt][nt] = (floatx4)0.0f;

#pragma unroll
    for (int ks = 0; ks < 4; ++ks) {
        bf16x8 bfrag[4];
#pragma unroll
        for (int nt = 0; nt < 4; ++nt) {
            int f = (ks + (wave >> 1) * 4) * 8 + (wave & 1) * 4 + nt;
            bfrag[nt] = WpF[f * 64 + lane];
        }
#pragma unroll
        for (int mt = 0; mt < 4; ++mt) {
            bf16x8 afrag = *reinterpret_cast<const bf16x8*>(
                &A[(mt * 16 + l15) * LDA + ks * 32 + quad * 8]);
#pragma unroll
            for (int nt = 0; nt < 4; ++nt)
                acc[mt][nt] = __builtin_amdgcn_mfma_f32_16x16x32_bf16(
                    afrag, bfrag[nt], acc[mt][nt], 0, 0, 0);
        }
    }

    // ---- store P (C layout: n=l15, m=quad*4+r) ----
#pragma unroll
    for (int mt = 0; mt < 4; ++mt)
#pragma unroll
        for (int r = 0; r < 4; ++r) {
            int node = node0 + mt * 16 + quad * 4 + r;
            if (node < Nn) {
#pragma unroll
                for (int nt = 0; nt < 4; ++nt) {
                    int np = wave * 64 + nt * 16 + l15;
                    P[(size_t)node * 256 + np] = (bf16_t)acc[mt][nt][r];
                }
            }
        }
}

// ===========================================================================
// K2: edge kernel. A = |zu-zv| (64x128), H = P[u][0:128] + P[v][128:256].
// 4 waves; wave w owns n-tiles {2w,2w+1}, all M. W1c = frags ks 8..11 of Wp.
// Gathers batched: 8 index loads, then 16 uint4 gathers in flight.
// ===========================================================================
__global__ __launch_bounds__(256, 4)
void edge_kernel(const bf16_t* __restrict__ zb,
                 const bf16_t* __restrict__ P,
                 const bf16_t* __restrict__ Wp,
                 const int* __restrict__ ei,
                 const float* __restrict__ b1,
                 const float* __restrict__ W2,
                 const float* __restrict__ b2,
                 float* __restrict__ out, int E) {
    __shared__ __align__(16) bf16_t A[E_TILE * LDA];   // 17408 B
    __shared__ __align__(16) bf16_t H[E_TILE * LDA];   // 17408 B
    __shared__ float red[4][E_TILE];                   // 1024 B

    const int tid = threadIdx.x;
    const int ebase = (int)blockIdx.x * E_TILE;
    const int r0 = tid >> 4;          // base row 0..15
    const int c  = (tid & 15) * 8;    // column offset (elements)

    // ---- batched gather: indices first, then all 16 row-loads ----
    int uu[4], vv[4];
#pragma unroll
    for (int i = 0; i < 4; ++i) {
        int e = ebase + i * 16 + r0; if (e >= E) e = E - 1;
        uu[i] = ei[e];
        vv[i] = ei[E + e];
    }
    uint4 gzu[4], gzv[4], gpa[4], gpb[4];
#pragma unroll
    for (int i = 0; i < 4; ++i) {
        gzu[i] = *reinterpret_cast<const uint4*>(zb + (size_t)uu[i] * DIM + c);
        gzv[i] = *reinterpret_cast<const uint4*>(zb + (size_t)vv[i] * DIM + c);
    }
#pragma unroll
    for (int i = 0; i < 4; ++i) {
        gpa[i] = *reinterpret_cast<const uint4*>(P + (size_t)uu[i] * 256 + c);
        gpb[i] = *reinterpret_cast<const uint4*>(P + (size_t)vv[i] * 256 + DIM + c);
    }
    // ---- convert A = |zu-zv| ----
#pragma unroll
    for (int i = 0; i < 4; ++i) {
        int m = i * 16 + r0;
        uint4 zu = gzu[i], zv = gzv[i];
        bf16x8 d;
        d[0]=(bf16_t)fabsf(bflo(zu.x)-bflo(zv.x));
        d[1]=(bf16_t)fabsf(bfhi(zu.x)-bfhi(zv.x));
        d[2]=(bf16_t)fabsf(bflo(zu.y)-bflo(zv.y));
        d[3]=(bf16_t)fabsf(bfhi(zu.y)-bfhi(zv.y));
        d[4]=(bf16_t)fabsf(bflo(zu.z)-bflo(zv.z));
        d[5]=(bf16_t)fabsf(bfhi(zu.z)-bfhi(zv.z));
        d[6]=(bf16_t)fabsf(bflo(zu.w)-bflo(zv.w));
        d[7]=(bf16_t)fabsf(bfhi(zu.w)-bfhi(zv.w));
        *reinterpret_cast<bf16x8*>(&A[m * LDA + c]) = d;
    }
    // ---- convert H = Pa + Pb ----
#pragma unroll
    for (int i = 0; i < 4; ++i) {
        int m = i * 16 + r0;
        uint4 pa = gpa[i], pb = gpb[i];
        bf16x8 h;
        h[0]=(bf16_t)(bflo(pa.x)+bflo(pb.x));
        h[1]=(bf16_t)(bfhi(pa.x)+bfhi(pb.x));
        h[2]=(bf16_t)(bflo(pa.y)+bflo(pb.y));
        h[3]=(bf16_t)(bfhi(pa.y)+bfhi(pb.y));
        h[4]=(bf16_t)(bflo(pa.z)+bflo(pb.z));
        h[5]=(bf16_t)(bfhi(pa.z)+bfhi(pb.z));
        h[6]=(bf16_t)(bflo(pa.w)+bflo(pb.w));
        h[7]=(bf16_t)(bfhi(pa.w)+bfhi(pb.w));
        *reinterpret_cast<bf16x8*>(&H[m * LDA + c]) = h;
    }
    __syncthreads();

    const int wave = tid >> 6, lane = tid & 63;
    const int l15 = lane & 15, quad = lane >> 4;

    float b1v[2], w2v[2];
#pragma unroll
    for (int nt = 0; nt < 2; ++nt) {
        int n = (wave * 2 + nt) * 16 + l15;
        b1v[nt] = b1[n];
        w2v[nt] = W2[n];
    }

    floatx4 acc[4][2];
#pragma unroll
    for (int mt = 0; mt < 4; ++mt)
#pragma unroll
        for (int nt = 0; nt < 2; ++nt) acc[mt][nt] = (floatx4)0.0f;

    const bf16x8* WpF = reinterpret_cast<const bf16x8*>(Wp);
#pragma unroll
    for (int ks = 0; ks < 4; ++ks) {
        bf16x8 bfrag[2];
#pragma unroll
        for (int nt = 0; nt < 2; ++nt)
            bfrag[nt] = WpF[((ks + 8) * 8 + wave * 2 + nt) * 64 + lane];
#pragma unroll
        for (int mt = 0; mt < 4; ++mt) {
            bf16x8 afrag = *reinterpret_cast<const bf16x8*>(
                &A[(mt * 16 + l15) * LDA + ks * 32 + quad * 8]);
#pragma unroll
            for (int nt = 0; nt < 2; ++nt)
                acc[mt][nt] = __builtin_amdgcn_mfma_f32_16x16x32_bf16(
                    afrag, bfrag[nt], acc[mt][nt], 0, 0, 0);
        }
    }

    // ---- epilogue: h = mfma + H + b1; relu; dot W2; 16-lane butterfly ----
    const unsigned short* Hs = reinterpret_cast<const unsigned short*>(H);
#pragma unroll
    for (int mt = 0; mt < 4; ++mt)
#pragma unroll
        for (int r = 0; r < 4; ++r) {
            int m = mt * 16 + quad * 4 + r;
            float s = 0.f;
#pragma unroll
            for (int nt = 0; nt < 2; ++nt) {
                int n = (wave * 2 + nt) * 16 + l15;
                float h = acc[mt][nt][r] + b1v[nt] + bf2f(Hs[m * LDA + n]);
                h = fmaxf(h, 0.f);
                s += h * w2v[nt];
            }
            s += __shfl_xor(s, 1);
            s += __shfl_xor(s, 2);
            s += __shfl_xor(s, 4);
            s += __shfl_xor(s, 8);
            if (l15 == 0) red[wave][m] = s;
        }
    __syncthreads();

    if (tid < E_TILE) {
        int e = ebase + tid;
        if (e < E) out[e] = red[0][tid] + red[1][tid] + red[2][tid] + red[3][tid] + b2[0];
    }
}

// ===========================================================================
// Fallback (r1-proven single-kernel path) if ws too small.
// ===========================================================================
#define ROW_ELEMS 392

__global__ __launch_bounds__(256)
void decode_fallback(const float* __restrict__ zsrc,
                     const int* __restrict__ ei,
                     const bf16_t* __restrict__ Wp,
                     const float* __restrict__ b1,
                     const float* __restrict__ W2,
                     const float* __restrict__ b2,
                     float* __restrict__ out, int E) {
    __shared__ __align__(16) bf16_t Atile[E_TILE * ROW_ELEMS];
    __shared__ float red[2][E_TILE];
    const int tid = threadIdx.x;
    const int ebase = blockIdx.x * E_TILE;
#pragma unroll
    for (int i = 0; i < 8; ++i) {
        int half  = i * 16 + (tid >> 4);
        int m     = half >> 1;
        int which = half & 1;
        int e = ebase + m; if (e >= E) e = E - 1;
        int node = ei[which * E + e];
        int l16 = tid & 15;
        bf16_t* dst = &Atile[m * ROW_ELEMS + which * DIM + l16 * 8];
        const float4* src = reinterpret_cast<const float4*>(
            zsrc + (size_t)node * DIM + l16 * 8);
        float4 a = src[0], b = src[1];
        bf16x8 o;
        o[0]=(bf16_t)a.x; o[1]=(bf16_t)a.y; o[2]=(bf16_t)a.z; o[3]=(bf16_t)a.w;
        o[4]=(bf16_t)b.x; o[5]=(bf16_t)b.y; o[6]=(bf16_t)b.z; o[7]=(bf16_t)b.w;
        *reinterpret_cast<bf16x8*>(dst) = o;
    }
    __syncthreads();
#pragma unroll
    for (int i = 0; i < 4; ++i) {
        int chunk = i * 256 + tid;
        int m  = chunk >> 4;
        int cc = (chunk & 15) * 8;
        uint4 au = *reinterpret_cast<const uint4*>(&Atile[m * ROW_ELEMS + cc]);
        uint4 av = *reinterpret_cast<const uint4*>(&Atile[m * ROW_ELEMS + DIM + cc]);
        bf16x8 d;
        d[0]=(bf16_t)fabsf(bflo(au.x)-bflo(av.x));
        d[1]=(bf16_t)fabsf(bfhi(au.x)-bfhi(av.x));
        d[2]=(bf16_t)fabsf(bflo(au.y)-bflo(av.y));
        d[3]=(bf16_t)fabsf(bfhi(au.y)-bfhi(av.y));
        d[4]=(bf16_t)fabsf(bflo(au.z)-bflo(av.z));
        d[5]=(bf16_t)fabsf(bfhi(au.z)-bfhi(av.z));
        d[6]=(bf16_t)fabsf(bflo(au.w)-bflo(av.w));
        d[7]=(bf16_t)fabsf(bfhi(au.w)-bfhi(av.w));
        *reinterpret_cast<bf16x8*>(&Atile[m * ROW_ELEMS + 2 * DIM + cc]) = d;
    }
    __syncthreads();
    const int wave = tid >> 6, lane = tid & 63;
    const int wm = wave >> 1, wn = wave & 1;
    const int l15 = lane & 15, quad = lane >> 4;
    floatx4 acc[2][4];
#pragma unroll
    for (int mt = 0; mt < 2; ++mt)
#pragma unroll
        for (int nt = 0; nt < 4; ++nt) acc[mt][nt] = (floatx4)0.0f;
    float b1v[4], w2v[4];
#pragma unroll
    for (int nt = 0; nt < 4; ++nt) {
        int n = (wn * 4 + nt) * 16 + l15;
        b1v[nt] = b1[n];
        w2v[nt] = W2[n];
    }
    const bf16x8* WpF = reinterpret_cast<const bf16x8*>(Wp);
#pragma unroll
    for (int ks = 0; ks < N_KSTEP; ++ks) {
        bf16x8 bfrag[4];
#pragma unroll
        for (int nt = 0; nt < 4; ++nt)
            bfrag[nt] = WpF[(ks * N_NTILE + wn * 4 + nt) * 64 + lane];
#pragma unroll
        for (int mt = 0; mt < 2; ++mt) {
            int m = wm * 32 + mt * 16 + l15;
            bf16x8 afrag = *reinterpret_cast<const bf16x8*>(
                &Atile[m * ROW_ELEMS + ks * 32 + quad * 8]);
#pragma unroll
            for (int nt = 0; nt < 4; ++nt)
                acc[mt][nt] = __builtin_amdgcn_mfma_f32_16x16x32_bf16(
                    afrag, bfrag[nt], acc[mt][nt], 0, 0, 0);
        }
    }
    float partial[2][4];
#pragma unroll
    for (int mt = 0; mt < 2; ++mt)
#pragma unroll
        for (int r = 0; r < 4; ++r) {
            float s = 0.f;
#pragma unroll
            for (int nt = 0; nt < 4; ++nt) {
                float h = acc[mt][nt][r] + b1v[nt];
                h = fmaxf(h, 0.f);
                s += h * w2v[nt];
            }
            s += __shfl_xor(s, 1);
            s += __shfl_xor(s, 2);
            s += __shfl_xor(s, 4);
            s += __shfl_xor(s, 8);
            partial[mt][r] = s;
        }
    if (l15 == 0) {
#pragma unroll
        for (int mt = 0; mt < 2; ++mt)
#pragma unroll
            for (int r = 0; r < 4; ++r) {
                int m = wm * 32 + mt * 16 + quad * 4 + r;
                red[wn][m] = partial[mt][r];
            }
    }
    __syncthreads();
    if (tid < E_TILE) {
        int e = ebase + tid;
        if (e < E) out[e] = red[0][tid] + red[1][tid] + b2[0];
    }
}

// ===========================================================================
extern "C" void kernel_launch(void* const* d_in, const int* in_sizes, int n_in,
                              void* d_out, int out_size, void* d_ws, size_t ws_size,
                              hipStream_t stream) {
    const float* z  = (const float*)d_in[0];
    const int*   ei = (const int*)d_in[1];
    const float* W1 = (const float*)d_in[2];
    const float* b1 = (const float*)d_in[3];
    const float* W2 = (const float*)d_in[4];
    const float* b2 = (const float*)d_in[5];
    float* out = (float*)d_out;

    const int E  = in_sizes[1] / 2;
    const int Nn = in_sizes[0] / DIM;

    const size_t wp_bytes = (size_t)N_KSTEP * N_NTILE * 64 * 16;   // 96 KB
    const size_t zb_bytes = (size_t)Nn * DIM * sizeof(bf16_t);     // 25.6 MB
    const size_t p_bytes  = (size_t)Nn * 256 * sizeof(bf16_t);     // 51.2 MB

    const int eblocks = (E + E_TILE - 1) / E_TILE;
    const int packblk = (N_KSTEP * N_NTILE * 64 + 255) / 256;      // 24

    bf16_t* wp = (bf16_t*)d_ws;
    hipLaunchKernelGGL(pack_w1_kernel, dim3(packblk), dim3(256), 0, stream, W1, wp);

    if (ws_size >= wp_bytes + zb_bytes + p_bytes) {
        bf16_t* zb = (bf16_t*)((char*)d_ws + wp_bytes);
        bf16_t* P  = (bf16_t*)((char*)d_ws + wp_bytes + zb_bytes);
        const int nblk = (Nn + NB_TILE - 1) / NB_TILE;
        hipLaunchKernelGGL(precompute_kernel, dim3(nblk), dim3(256), 0, stream,
                           z, wp, zb, P, Nn);
        hipLaunchKernelGGL(edge_kernel, dim3(eblocks), dim3(256), 0, stream,
                           zb, P, wp, ei, b1, W2, b2, out, E);
    } else {
        hipLaunchKernelGGL(decode_fallback, dim3(eblocks), dim3(256), 0, stream,
                           z, ei, wp, b1, W2, b2, out, E);
    }
}